// Round 2
// baseline (412.819 us; speedup 1.0000x reference)
//
#include <hip/hip_runtime.h>

// ---------------------------------------------------------------------------
// SelfAttention (distance-based, transposed accumulation), MI355X bf16 MFMA.
// B=4, S=2048, F=512, H=8, DH=64, OUT=512.
//
// Math: q=xWq, k=xWk, v=xWv (+biases).  q~ = q*2*log2e (prescaled)
//   s2[i,j] = q~_i.k_j - k2l[j],  k2l = log2e*|k_j|^2   (q2 cancels in softmax)
//   p[i,j] = exp2(s2[i,j])  (raw; s ~ -64 +- 20 so no overflow)
//   invl[i] = 1/sum_j p[i,j];  v~[i,d] = invl[i]*v[i,d]
//   attn[j,d] = sum_i p[i,j] v~[i,d]          (note: output index is j)
//   out = leakyrelu(attn @ Wo + bo, 0.01)
// ---------------------------------------------------------------------------

typedef __attribute__((ext_vector_type(8))) short bf16x8;
typedef __attribute__((ext_vector_type(4))) float f32x4;
typedef __attribute__((ext_vector_type(2))) unsigned int u32x2;
typedef __attribute__((ext_vector_type(4))) unsigned int u32x4;

#define MFMA16 __builtin_amdgcn_mfma_f32_16x16x32_bf16
#define LOG2E 1.4426950408889634f
#define TWO_LOG2E 2.8853900817779268f

__device__ inline unsigned short f2bf(float f) {
  unsigned int u = __float_as_uint(f);
  unsigned int r = 0x7fffu + ((u >> 16) & 1u);
  return (unsigned short)((u + r) >> 16);
}
__device__ inline float bf2f(unsigned short h) {
  return __uint_as_float(((unsigned int)h) << 16);
}
__device__ inline float fexp2(float x) { return __builtin_amdgcn_exp2f(x); }

// async global->LDS, 16B per lane. lds base must be wave-uniform.
__device__ inline void gl_lds16(const unsigned short* g, unsigned short* lds) {
  __builtin_amdgcn_global_load_lds(
      (const __attribute__((address_space(1))) unsigned int*)g,
      (__attribute__((address_space(3))) unsigned int*)lds, 16, 0, 0);
}

// ---------------------------------------------------------------------------
// prep: cast x to bf16, pack W^T (bf16) for qkv and out proj, pack biases.
// ---------------------------------------------------------------------------
#define NXB (8192*512)
#define NWQ (1536*512)
#define NWO (512*512)

__global__ __launch_bounds__(256) void prep(
    const float* __restrict__ x, const float* __restrict__ Wq,
    const float* __restrict__ Wk, const float* __restrict__ Wv,
    const float* __restrict__ Wo, const float* __restrict__ bq,
    const float* __restrict__ bk, const float* __restrict__ bv,
    unsigned short* __restrict__ xb, unsigned short* __restrict__ wqkvT,
    unsigned short* __restrict__ woT, float* __restrict__ biasp) {
  int i = blockIdx.x * blockDim.x + threadIdx.x;
  if (i < NXB) { xb[i] = f2bf(x[i]); return; }
  i -= NXB;
  if (i < NWQ) {  // wqkvT[n][f] = W(f, n%512), n in [0,1536)
    int n = i >> 9, f = i & 511;
    const float* W = (n < 512) ? Wq : (n < 1024) ? Wk : Wv;
    wqkvT[i] = f2bf(W[f * 512 + (n & 511)]);
    return;
  }
  i -= NWQ;
  if (i < NWO) {  // woT[o][hd] = Wo[hd][o]
    int o = i >> 9, hd = i & 511;
    woT[i] = f2bf(Wo[hd * 512 + o]);
    return;
  }
  i -= NWO;
  if (i < 1536) {
    biasp[i] = (i < 512) ? bq[i] : (i < 1024) ? bk[i - 512] : bv[i - 1024];
  }
}

// ---------------------------------------------------------------------------
// GEMM C[M,N] = A[M,K] * Bt[N,K]^T + bias, bf16 in, f32 acc. 128x128 tile.
// MODE 0: scatter bf16 into q~/k/v [bh][s][d] (q scaled by 2*log2e).
// MODE 1: bias + leaky-relu, f32 out.
// ---------------------------------------------------------------------------
template<int MODE>
__global__ __launch_bounds__(256) void gemm_bt(
    const unsigned short* __restrict__ A, const unsigned short* __restrict__ Bt,
    const float* __restrict__ bias,
    unsigned short* __restrict__ o_q, unsigned short* __restrict__ o_k,
    unsigned short* __restrict__ o_v, float* __restrict__ o_f, int K) {
  const int m0 = blockIdx.y * 128;
  const int n0 = blockIdx.x * 128;
  const int tid = threadIdx.x;
  const int w = tid >> 6, l = tid & 63, lg = l >> 4, ll = l & 15;
  const int wr = w >> 1, wc = w & 1;
  __shared__ unsigned short a_lds[128 * 32];
  __shared__ unsigned short b_lds[128 * 32];
  f32x4 acc[4][4] = {};
  const int nkt = K >> 5;
  for (int kt = 0; kt < nkt; ++kt) {
#pragma unroll
    for (int c = 0; c < 2; ++c) {
      const int cc_base = c * 256 + w * 64;
      const int cc = cc_base + l;
      const int row = cc >> 2, cl = cc & 3;
      gl_lds16(A + (size_t)(m0 + row) * K + kt * 32 + cl * 8, a_lds + cc_base * 8);
      gl_lds16(Bt + (size_t)(n0 + row) * K + kt * 32 + cl * 8, b_lds + cc_base * 8);
    }
    __syncthreads();
    bf16x8 af[4], bfr[4];
#pragma unroll
    for (int mi = 0; mi < 4; ++mi)
      af[mi] = *(const bf16x8*)(a_lds + (wr * 64 + mi * 16 + ll) * 32 + lg * 8);
#pragma unroll
    for (int ni = 0; ni < 4; ++ni)
      bfr[ni] = *(const bf16x8*)(b_lds + (wc * 64 + ni * 16 + ll) * 32 + lg * 8);
#pragma unroll
    for (int mi = 0; mi < 4; ++mi)
#pragma unroll
      for (int ni = 0; ni < 4; ++ni)
        acc[mi][ni] = MFMA16(af[mi], bfr[ni], acc[mi][ni], 0, 0, 0);
    __syncthreads();
  }
#pragma unroll
  for (int mi = 0; mi < 4; ++mi)
#pragma unroll
    for (int ni = 0; ni < 4; ++ni) {
      const int col = n0 + wc * 64 + ni * 16 + ll;
      const float bb = bias[col];
#pragma unroll
      for (int r = 0; r < 4; ++r) {
        const int row = m0 + wr * 64 + mi * 16 + lg * 4 + r;
        float v = acc[mi][ni][r] + bb;
        if (MODE == 0) {
          const int which = col >> 9, h = (col >> 6) & 7, d = col & 63;
          const int b = row >> 11, s = row & 2047;
          if (which == 0) v *= TWO_LOG2E;  // q prescale
          const size_t idx = ((size_t)((b * 8 + h) * 2048 + s)) * 64 + d;
          (which == 0 ? o_q : which == 1 ? o_k : o_v)[idx] = f2bf(v);
        } else {
          v = v >= 0.f ? v : 0.01f * v;
          o_f[(size_t)row * 512 + col] = v;
        }
      }
    }
}

// ---------------------------------------------------------------------------
// k2l[row] = log2e * sum_d k[row][d]^2   (rows = BH*S = 65536)
// ---------------------------------------------------------------------------
__global__ __launch_bounds__(256) void k2_kernel(const unsigned short* __restrict__ k_g,
                                                 float* __restrict__ k2l_g) {
  const int lane = threadIdx.x & 63;
  const int wid = (blockIdx.x * blockDim.x + threadIdx.x) >> 6;
  const int nw = (gridDim.x * blockDim.x) >> 6;
  for (int row = wid; row < 32 * 2048; row += nw) {
    float v = bf2f(k_g[(size_t)row * 64 + lane]);
    v *= v;
#pragma unroll
    for (int m = 1; m < 64; m <<= 1) v += __shfl_xor(v, m);
    if (lane == 0) k2l_g[row] = LOG2E * v;
  }
}

// ---------------------------------------------------------------------------
// pass1: invl[i] = 1 / sum_j exp2(q~_i.k_j - k2l[j]).
// Barrier-free, LDS-free. 4 waves x 16 i. A=Q (regs), B=K swept from global.
// C layout: lane(lg,ll): i = w*16+lg*4+r, j = jt*64+nf*16+ll.
// ---------------------------------------------------------------------------
__global__ __launch_bounds__(256) void pass1(const unsigned short* __restrict__ q_g,
                                             const unsigned short* __restrict__ k_g,
                                             const float* __restrict__ k2l_g,
                                             float* __restrict__ invl_g) {
  const int bh = blockIdx.x >> 5, ib = blockIdx.x & 31;
  const int i0 = ib * 64;
  const int tid = threadIdx.x, w = tid >> 6, l = tid & 63, lg = l >> 4, ll = l & 15;
  const unsigned short* qrow = q_g + ((size_t)(bh * 2048 + i0 + w * 16 + ll)) * 64 + lg * 8;
  const bf16x8 qa0 = *(const bf16x8*)(qrow);
  const bf16x8 qa1 = *(const bf16x8*)(qrow + 32);
  const unsigned short* kp = k_g + ((size_t)(bh * 2048 + ll)) * 64 + lg * 8;
  const float* k2p = k2l_g + bh * 2048 + ll;
  f32x4 lrun = {0.f, 0.f, 0.f, 0.f};
  for (int jt = 0; jt < 32; ++jt) {
    bf16x8 kb[4][2];
    float k2v[4];
#pragma unroll
    for (int nf = 0; nf < 4; ++nf) {
      kb[nf][0] = *(const bf16x8*)(kp + nf * 1024);
      kb[nf][1] = *(const bf16x8*)(kp + nf * 1024 + 32);
      k2v[nf] = k2p[nf * 16];
    }
#pragma unroll
    for (int nf = 0; nf < 4; ++nf) {
      f32x4 sa = {};
      sa = MFMA16(qa0, kb[nf][0], sa, 0, 0, 0);
      sa = MFMA16(qa1, kb[nf][1], sa, 0, 0, 0);
      lrun[0] += fexp2(sa[0] - k2v[nf]);
      lrun[1] += fexp2(sa[1] - k2v[nf]);
      lrun[2] += fexp2(sa[2] - k2v[nf]);
      lrun[3] += fexp2(sa[3] - k2v[nf]);
    }
    kp += 64 * 64;
    k2p += 64;
  }
#pragma unroll
  for (int r = 0; r < 4; ++r) {
    float t = lrun[r];
#pragma unroll
    for (int m = 1; m < 16; m <<= 1) t += __shfl_xor(t, m);
    if (ll == 0) invl_g[bh * 2048 + i0 + w * 16 + lg * 4 + r] = 1.f / t;
  }
}

// ---------------------------------------------------------------------------
// transpose_v: vT~[bh][d][s] = invl[s] * v[bh][s][d]
// ---------------------------------------------------------------------------
__global__ __launch_bounds__(256) void transpose_v(const unsigned short* __restrict__ v_g,
                                                   const float* __restrict__ invl_g,
                                                   unsigned short* __restrict__ vt_g) {
  const int bh = blockIdx.x >> 5, st = blockIdx.x & 31;
  const int s0 = st * 64;
  __shared__ unsigned short tile[64][72];
  const int t = threadIdx.x;
  {
    const int sl = t >> 2, cg = t & 3;
    const float sc = invl_g[bh * 2048 + s0 + sl];
    const unsigned short* src = v_g + ((size_t)(bh * 2048 + s0 + sl)) * 64 + cg * 16;
    bf16x8 v0 = *(const bf16x8*)(src);
    bf16x8 v1 = *(const bf16x8*)(src + 8);
#pragma unroll
    for (int e = 0; e < 8; ++e) tile[sl][cg * 16 + e] = f2bf(sc * bf2f((unsigned short)v0[e]));
#pragma unroll
    for (int e = 0; e < 8; ++e) tile[sl][cg * 16 + 8 + e] = f2bf(sc * bf2f((unsigned short)v1[e]));
  }
  __syncthreads();
  {
    const int dl = t >> 2, sg = t & 3;
    bf16x8 o0, o1;
#pragma unroll
    for (int e = 0; e < 8; ++e) o0[e] = (short)tile[sg * 16 + e][dl];
#pragma unroll
    for (int e = 0; e < 8; ++e) o1[e] = (short)tile[sg * 16 + 8 + e][dl];
    unsigned short* dst = vt_g + ((size_t)(bh * 64 + dl)) * 2048 + s0 + sg * 16;
    *(bf16x8*)dst = o0;
    *(bf16x8*)(dst + 8) = o1;
  }
}

// ---------------------------------------------------------------------------
// pass2: attn[j,d] = sum_i exp2(q~_i.k_j - k2l[j]) * v~[i,d]
// Barrier-free, LDS-free. Per wave: 16 j's; K B-frags + k2l per-lane const.
// S = mfma(Q, K): lane(lg,ll): i = it*64+nf*16+lg*4+r, j = j0+w*16+ll.
// P -> bf16 via v_cvt_pk; PV A-frag built in-register with
// permlane32_swap (^32) + ds_swizzle (^16) + cndmask (T12 pattern).
// ---------------------------------------------------------------------------
__global__ __launch_bounds__(256) void pass2(const unsigned short* __restrict__ q_g,
                                             const unsigned short* __restrict__ k_g,
                                             const unsigned short* __restrict__ vt_g,
                                             const float* __restrict__ k2l_g,
                                             unsigned short* __restrict__ attnb) {
  const int bh = blockIdx.x >> 5, jb = blockIdx.x & 31;
  const int j0 = jb * 64;
  const int tid = threadIdx.x, w = tid >> 6, l = tid & 63, lg = l >> 4, ll = l & 15;
  const unsigned short* krow = k_g + ((size_t)(bh * 2048 + j0 + w * 16 + ll)) * 64 + lg * 8;
  const bf16x8 kb0 = *(const bf16x8*)(krow);
  const bf16x8 kb1 = *(const bf16x8*)(krow + 32);
  const float k2l = k2l_g[bh * 2048 + j0 + w * 16 + ll];
  const bool odd = (lg & 1) != 0;
  f32x4 oacc[4] = {};
  const unsigned short* qp = q_g + ((size_t)(bh * 2048 + ll)) * 64 + lg * 8;
  const unsigned short* vp = vt_g + ((size_t)(bh * 64 + ll)) * 2048 + lg * 8;
#pragma unroll 1
  for (int it = 0; it < 32; ++it) {
    bf16x8 aq[4][2], bvf[4][2];
#pragma unroll
    for (int nf = 0; nf < 4; ++nf) {
      aq[nf][0] = *(const bf16x8*)(qp + nf * 1024);
      aq[nf][1] = *(const bf16x8*)(qp + nf * 1024 + 32);
      bvf[nf][0] = *(const bf16x8*)(vp + nf * 32768);
      bvf[nf][1] = *(const bf16x8*)(vp + nf * 32768 + 32);
    }
    unsigned int pk[4][2];
#pragma unroll
    for (int nf = 0; nf < 4; ++nf) {
      f32x4 sa = {};
      sa = MFMA16(aq[nf][0], kb0, sa, 0, 0, 0);
      sa = MFMA16(aq[nf][1], kb1, sa, 0, 0, 0);
      float p0 = fexp2(sa[0] - k2l);
      float p1 = fexp2(sa[1] - k2l);
      float p2 = fexp2(sa[2] - k2l);
      float p3 = fexp2(sa[3] - k2l);
      asm("v_cvt_pk_bf16_f32 %0, %1, %2" : "=v"(pk[nf][0]) : "v"(p0), "v"(p1));
      asm("v_cvt_pk_bf16_f32 %0, %1, %2" : "=v"(pk[nf][1]) : "v"(p2), "v"(p3));
    }
    bf16x8 pa[2];
#pragma unroll
    for (int hh = 0; hh < 2; ++hh) {
      u32x2 r0 = __builtin_amdgcn_permlane32_swap(pk[2 * hh][0], pk[2 * hh + 1][0], false, false);
      u32x2 r1 = __builtin_amdgcn_permlane32_swap(pk[2 * hh][1], pk[2 * hh + 1][1], false, false);
      unsigned int s_r0l = (unsigned int)__builtin_amdgcn_ds_swizzle((int)r0[0], 0x401F);
      unsigned int s_r0h = (unsigned int)__builtin_amdgcn_ds_swizzle((int)r0[1], 0x401F);
      unsigned int s_r1l = (unsigned int)__builtin_amdgcn_ds_swizzle((int)r1[0], 0x401F);
      unsigned int s_r1h = (unsigned int)__builtin_amdgcn_ds_swizzle((int)r1[1], 0x401F);
      u32x4 a;
      a.x = odd ? s_r0h : r0[0];
      a.y = odd ? s_r1h : r1[0];
      a.z = odd ? r0[1] : s_r0l;
      a.w = odd ? r1[1] : s_r1l;
      pa[hh] = __builtin_bit_cast(bf16x8, a);
    }
#pragma unroll
    for (int nf = 0; nf < 4; ++nf) {
      oacc[nf] = MFMA16(pa[0], bvf[nf][0], oacc[nf], 0, 0, 0);
      oacc[nf] = MFMA16(pa[1], bvf[nf][1], oacc[nf], 0, 0, 0);
    }
    qp += 64 * 64;
    vp += 64;
  }
  const int b = bh >> 3, h2 = bh & 7;
#pragma unroll
  for (int nf = 0; nf < 4; ++nf)
#pragma unroll
    for (int r = 0; r < 4; ++r) {
      const int j = j0 + w * 16 + lg * 4 + r;
      attnb[((size_t)(b * 2048 + j)) * 512 + h2 * 64 + nf * 16 + ll] = f2bf(oacc[nf][r]);
    }
}

// ---------------------------------------------------------------------------
extern "C" void kernel_launch(void* const* d_in, const int* in_sizes, int n_in,
                              void* d_out, int out_size, void* d_ws, size_t ws_size,
                              hipStream_t stream) {
  const float* x  = (const float*)d_in[0];
  const float* Wq = (const float*)d_in[1];
  const float* bq = (const float*)d_in[2];
  const float* Wk = (const float*)d_in[3];
  const float* bk = (const float*)d_in[4];
  const float* Wv = (const float*)d_in[5];
  const float* bv = (const float*)d_in[6];
  const float* Wo = (const float*)d_in[7];
  const float* bo = (const float*)d_in[8];
  float* out = (float*)d_out;
  char* ws = (char*)d_ws;

  unsigned short* xb    = (unsigned short*)(ws);
  unsigned short* wqkvT = (unsigned short*)(ws + 8388608);
  unsigned short* woT   = (unsigned short*)(ws + 9961472);
  float*          biasp = (float*)         (ws + 10485760);
  unsigned short* q_g   = (unsigned short*)(ws + 10493952);
  unsigned short* k_g   = (unsigned short*)(ws + 18882560);
  unsigned short* v_g   = (unsigned short*)(ws + 27271168);
  unsigned short* vt_g  = (unsigned short*)(ws + 35659776);
  float*          k2_g  = (float*)         (ws + 44048384);
  float*          invl_g= (float*)         (ws + 44310528);
  unsigned short* attnb = (unsigned short*)(ws + 44572672);
  if (ws_size < (size_t)52961280) return;

  prep<<<20486, 256, 0, stream>>>(x, Wq, Wk, Wv, Wo, bq, bk, bv, xb, wqkvT, woT, biasp);
  gemm_bt<0><<<dim3(12, 64), 256, 0, stream>>>(xb, wqkvT, biasp, q_g, k_g, v_g, nullptr, 512);
  k2_kernel<<<1024, 256, 0, stream>>>(k_g, k2_g);
  pass1<<<1024, 256, 0, stream>>>(q_g, k_g, k2_g, invl_g);
  transpose_v<<<1024, 256, 0, stream>>>(v_g, invl_g, vt_g);
  pass2<<<1024, 256, 0, stream>>>(q_g, k_g, vt_g, k2_g, attnb);
  gemm_bt<1><<<dim3(4, 64), 256, 0, stream>>>(attnb, woT, bo, nullptr, nullptr, nullptr, out, 512);
}

// Round 6
// 167.312 us; speedup vs baseline: 2.4674x; 2.4674x over previous
//
#include <hip/hip_runtime.h>

// ---------------------------------------------------------------------------
// SelfAttention (distance-based, transposed accumulation), MI355X bf16 MFMA.
// B=4, S=2048, F=512, H=8, DH=64, OUT=512.
//
// ROUND 6 = ROUND 1 SOURCE VERBATIM + constant folds ONLY:
//   q~ = q*2*log2e (gemm epilogue), k2l = log2e*k2 (k2_kernel),
//   v~ = invl*v (transpose_v, round-2 code, launched after pass1),
//   exp lines become exp2(sa - k2l), pass2 drops iv[] loads.
// NO other changes: staging, sync, fragment maps, P->LDS round trip all
// exactly round 1 (validated at 202us).
// ---------------------------------------------------------------------------

typedef __attribute__((ext_vector_type(8))) short bf16x8;
typedef __attribute__((ext_vector_type(4))) float f32x4;

#define MFMA16 __builtin_amdgcn_mfma_f32_16x16x32_bf16
#define LOG2E 1.4426950408889634f
#define TWO_LOG2E 2.8853900817779268f

__device__ inline unsigned short f2bf(float f) {
  unsigned int u = __float_as_uint(f);
  unsigned int r = 0x7fffu + ((u >> 16) & 1u);
  return (unsigned short)((u + r) >> 16);
}
__device__ inline float bf2f(unsigned short h) {
  return __uint_as_float(((unsigned int)h) << 16);
}
__device__ inline float fexp2(float x) { return __builtin_amdgcn_exp2f(x); }

// async global->LDS, 16B per lane. lds base must be wave-uniform.
__device__ inline void gl_lds16(const unsigned short* g, unsigned short* lds) {
  __builtin_amdgcn_global_load_lds(
      (const __attribute__((address_space(1))) unsigned int*)g,
      (__attribute__((address_space(3))) unsigned int*)lds, 16, 0, 0);
}

// ---------------------------------------------------------------------------
// prep: cast x to bf16, pack W^T (bf16) for qkv and out proj, pack biases.
// (round 1 verbatim)
// ---------------------------------------------------------------------------
#define NXB (8192*512)
#define NWQ (1536*512)
#define NWO (512*512)

__global__ __launch_bounds__(256) void prep(
    const float* __restrict__ x, const float* __restrict__ Wq,
    const float* __restrict__ Wk, const float* __restrict__ Wv,
    const float* __restrict__ Wo, const float* __restrict__ bq,
    const float* __restrict__ bk, const float* __restrict__ bv,
    unsigned short* __restrict__ xb, unsigned short* __restrict__ wqkvT,
    unsigned short* __restrict__ woT, float* __restrict__ biasp) {
  int i = blockIdx.x * blockDim.x + threadIdx.x;
  if (i < NXB) { xb[i] = f2bf(x[i]); return; }
  i -= NXB;
  if (i < NWQ) {  // wqkvT[n][f] = W(f, n%512), n in [0,1536)
    int n = i >> 9, f = i & 511;
    const float* W = (n < 512) ? Wq : (n < 1024) ? Wk : Wv;
    wqkvT[i] = f2bf(W[f * 512 + (n & 511)]);
    return;
  }
  i -= NWQ;
  if (i < NWO) {  // woT[o][hd] = Wo[hd][o]
    int o = i >> 9, hd = i & 511;
    woT[i] = f2bf(Wo[hd * 512 + o]);
    return;
  }
  i -= NWO;
  if (i < 1536) {
    biasp[i] = (i < 512) ? bq[i] : (i < 1024) ? bk[i - 512] : bv[i - 1024];
  }
}

// ---------------------------------------------------------------------------
// GEMM C[M,N] = A[M,K] * Bt[N,K]^T + bias (round 1 verbatim + q prescale).
// MODE 0: scatter bf16 into q~/k/v [bh][s][d].  MODE 1: bias+leakyrelu f32.
// ---------------------------------------------------------------------------
template<int MODE>
__global__ __launch_bounds__(256) void gemm_bt(
    const unsigned short* __restrict__ A, const unsigned short* __restrict__ Bt,
    const float* __restrict__ bias,
    unsigned short* __restrict__ o_q, unsigned short* __restrict__ o_k,
    unsigned short* __restrict__ o_v, float* __restrict__ o_f, int K) {
  const int m0 = blockIdx.y * 128;
  const int n0 = blockIdx.x * 128;
  const int tid = threadIdx.x;
  const int w = tid >> 6, l = tid & 63, lg = l >> 4, ll = l & 15;
  const int wr = w >> 1, wc = w & 1;
  __shared__ unsigned short a_lds[128 * 32];
  __shared__ unsigned short b_lds[128 * 32];
  f32x4 acc[4][4] = {};
  const int nkt = K >> 5;
  for (int kt = 0; kt < nkt; ++kt) {
#pragma unroll
    for (int c = 0; c < 2; ++c) {
      const int cc_base = c * 256 + w * 64;
      const int cc = cc_base + l;
      const int row = cc >> 2, cl = cc & 3;
      gl_lds16(A + (size_t)(m0 + row) * K + kt * 32 + cl * 8, a_lds + cc_base * 8);
      gl_lds16(Bt + (size_t)(n0 + row) * K + kt * 32 + cl * 8, b_lds + cc_base * 8);
    }
    __syncthreads();
    bf16x8 af[4], bfr[4];
#pragma unroll
    for (int mi = 0; mi < 4; ++mi)
      af[mi] = *(const bf16x8*)(a_lds + (wr * 64 + mi * 16 + ll) * 32 + lg * 8);
#pragma unroll
    for (int ni = 0; ni < 4; ++ni)
      bfr[ni] = *(const bf16x8*)(b_lds + (wc * 64 + ni * 16 + ll) * 32 + lg * 8);
#pragma unroll
    for (int mi = 0; mi < 4; ++mi)
#pragma unroll
      for (int ni = 0; ni < 4; ++ni)
        acc[mi][ni] = MFMA16(af[mi], bfr[ni], acc[mi][ni], 0, 0, 0);
    __syncthreads();
  }
#pragma unroll
  for (int mi = 0; mi < 4; ++mi)
#pragma unroll
    for (int ni = 0; ni < 4; ++ni) {
      const int col = n0 + wc * 64 + ni * 16 + ll;
      const float bb = bias[col];
#pragma unroll
      for (int r = 0; r < 4; ++r) {
        const int row = m0 + wr * 64 + mi * 16 + lg * 4 + r;
        float v = acc[mi][ni][r] + bb;
        if (MODE == 0) {
          const int which = col >> 9, h = (col >> 6) & 7, d = col & 63;
          const int b = row >> 11, s = row & 2047;
          if (which == 0) v *= TWO_LOG2E;  // q prescale (round-2 validated)
          const size_t idx = ((size_t)((b * 8 + h) * 2048 + s)) * 64 + d;
          (which == 0 ? o_q : which == 1 ? o_k : o_v)[idx] = f2bf(v);
        } else {
          v = v >= 0.f ? v : 0.01f * v;
          o_f[(size_t)row * 512 + col] = v;
        }
      }
    }
}

// ---------------------------------------------------------------------------
// k2l[row] = log2e * sum_d k[row][d]^2   (round 1 verbatim + LOG2E fold)
// ---------------------------------------------------------------------------
__global__ __launch_bounds__(256) void k2_kernel(const unsigned short* __restrict__ k_g,
                                                 float* __restrict__ k2l_g) {
  const int lane = threadIdx.x & 63;
  const int wid = (blockIdx.x * blockDim.x + threadIdx.x) >> 6;
  const int nw = (gridDim.x * blockDim.x) >> 6;
  for (int row = wid; row < 32 * 2048; row += nw) {
    float v = bf2f(k_g[(size_t)row * 64 + lane]);
    v *= v;
#pragma unroll
    for (int m = 1; m < 64; m <<= 1) v += __shfl_xor(v, m);
    if (lane == 0) k2l_g[row] = LOG2E * v;
  }
}

// ---------------------------------------------------------------------------
// transpose_v: vT~[bh][d][s] = invl[s] * v[bh][s][d]  (round 2 verbatim)
// ---------------------------------------------------------------------------
__global__ __launch_bounds__(256) void transpose_v(const unsigned short* __restrict__ v_g,
                                                   const float* __restrict__ invl_g,
                                                   unsigned short* __restrict__ vt_g) {
  const int bh = blockIdx.x >> 5, st = blockIdx.x & 31;
  const int s0 = st * 64;
  __shared__ unsigned short tile[64][72];
  const int t = threadIdx.x;
  {
    const int sl = t >> 2, cg = t & 3;
    const float sc = invl_g[bh * 2048 + s0 + sl];
    const unsigned short* src = v_g + ((size_t)(bh * 2048 + s0 + sl)) * 64 + cg * 16;
    bf16x8 v0 = *(const bf16x8*)(src);
    bf16x8 v1 = *(const bf16x8*)(src + 8);
#pragma unroll
    for (int e = 0; e < 8; ++e) tile[sl][cg * 16 + e] = f2bf(sc * bf2f((unsigned short)v0[e]));
#pragma unroll
    for (int e = 0; e < 8; ++e) tile[sl][cg * 16 + 8 + e] = f2bf(sc * bf2f((unsigned short)v1[e]));
  }
  __syncthreads();
  {
    const int dl = t >> 2, sg = t & 3;
    bf16x8 o0, o1;
#pragma unroll
    for (int e = 0; e < 8; ++e) o0[e] = (short)tile[sg * 16 + e][dl];
#pragma unroll
    for (int e = 0; e < 8; ++e) o1[e] = (short)tile[sg * 16 + 8 + e][dl];
    unsigned short* dst = vt_g + ((size_t)(bh * 64 + dl)) * 2048 + s0 + sg * 16;
    *(bf16x8*)dst = o0;
    *(bf16x8*)(dst + 8) = o1;
  }
}

// ---------------------------------------------------------------------------
// pass1: invl[i] = 1 / sum_j exp2(q~_i.k_j - k2l[j])
// ROUND 1 VERBATIM (k_lds + k2_lds staging, same sync); only the exp line
// changed from exp2f((2*sa-k2)*LOG2E) to fexp2(sa-k2l).
// ---------------------------------------------------------------------------
__global__ __launch_bounds__(256) void pass1(const unsigned short* __restrict__ q_g,
                                             const unsigned short* __restrict__ k_g,
                                             const float* __restrict__ k2l_g,
                                             float* __restrict__ invl_g) {
  const int bh = blockIdx.x >> 5, ib = blockIdx.x & 31;
  const int i0 = ib * 64;
  const int tid = threadIdx.x, w = tid >> 6, l = tid & 63, lg = l >> 4, ll = l & 15;
  __shared__ unsigned short k_lds[64 * 64];
  __shared__ float k2_lds[64];
  const unsigned short* qrow = q_g + ((size_t)(bh * 2048 + i0 + w * 16 + ll)) * 64;
  const bf16x8 qa0 = *(const bf16x8*)(qrow + lg * 8);
  const bf16x8 qa1 = *(const bf16x8*)(qrow + 32 + lg * 8);
  float lrun[4] = {0.f, 0.f, 0.f, 0.f};
  for (int jt = 0; jt < 32; ++jt) {
    const int j0 = jt * 64;
#pragma unroll
    for (int c = 0; c < 2; ++c) {
      const int cc_base = c * 256 + w * 64;
      const int cc = cc_base + l;
      const int row = cc >> 3, cl = cc & 7;
      gl_lds16(k_g + ((size_t)(bh * 2048 + j0 + row)) * 64 + ((cl ^ (row & 7)) * 8),
               k_lds + cc_base * 8);
    }
    if (tid < 64) k2_lds[tid] = k2l_g[bh * 2048 + j0 + tid];
    __syncthreads();
#pragma unroll
    for (int nf = 0; nf < 4; ++nf) {
      const int jr = nf * 16 + ll;
      const unsigned short* kb = k_lds + jr * 64;
      const int sw = jr & 7;
      bf16x8 b0 = *(const bf16x8*)(kb + ((lg ^ sw) * 8));
      bf16x8 b1 = *(const bf16x8*)(kb + (((4 + lg) ^ sw) * 8));
      f32x4 sa = {};
      sa = MFMA16(qa0, b0, sa, 0, 0, 0);
      sa = MFMA16(qa1, b1, sa, 0, 0, 0);
      const float k2v = k2_lds[jr];
      lrun[0] += fexp2(sa[0] - k2v);
      lrun[1] += fexp2(sa[1] - k2v);
      lrun[2] += fexp2(sa[2] - k2v);
      lrun[3] += fexp2(sa[3] - k2v);
    }
    __syncthreads();
  }
#pragma unroll
  for (int r = 0; r < 4; ++r) {
    float t = lrun[r];
#pragma unroll
    for (int m = 1; m < 16; m <<= 1) t += __shfl_xor(t, m);
    if (ll == 0) invl_g[bh * 2048 + i0 + w * 16 + lg * 4 + r] = 1.f / t;
  }
}

// ---------------------------------------------------------------------------
// pass2: attn[j,d] = sum_i exp2(q~_i.k_j - k2l[j]) * v~[i,d]
// ROUND 1 VERBATIM (scores S^T via mfma(K,Q), P^T through swizzled LDS,
// PV against vT~ tiles, same staging/sync); only changes: exp line
// fexp2(sa-k2l) and iv[] loads/multiply removed (invl folded into v~).
// ---------------------------------------------------------------------------
__global__ __launch_bounds__(256) void pass2(const unsigned short* __restrict__ q_g,
                                             const unsigned short* __restrict__ k_g,
                                             const unsigned short* __restrict__ vt_g,
                                             const float* __restrict__ k2l_g,
                                             unsigned short* __restrict__ attnb) {
  const int bh = blockIdx.x >> 5, jb = blockIdx.x & 31;
  const int j0 = jb * 64;
  const int tid = threadIdx.x, w = tid >> 6, l = tid & 63, lg = l >> 4, ll = l & 15;
  __shared__ unsigned short q_lds[64 * 64];
  __shared__ unsigned short vt_lds[64 * 64];
  __shared__ unsigned short p_lds[64 * 64];
  // K A-frags: rows j = j0 + w*16 + ll, in registers for whole kernel
  const unsigned short* krow = k_g + ((size_t)(bh * 2048 + j0 + w * 16 + ll)) * 64;
  const bf16x8 ka0 = *(const bf16x8*)(krow + lg * 8);
  const bf16x8 ka1 = *(const bf16x8*)(krow + 32 + lg * 8);
  float k2v[4];
#pragma unroll
  for (int r = 0; r < 4; ++r) k2v[r] = k2l_g[bh * 2048 + j0 + w * 16 + lg * 4 + r];
  f32x4 oacc[4] = {};
  const unsigned short* vt_base = vt_g + (size_t)bh * 64 * 2048;
  for (int it = 0; it < 32; ++it) {
    const int i0 = it * 64;
#pragma unroll
    for (int c = 0; c < 2; ++c) {
      const int cc_base = c * 256 + w * 64;
      const int cc = cc_base + l;
      const int row = cc >> 3, cl = cc & 7;
      const int csw = (cl ^ (row & 7)) * 8;
      gl_lds16(q_g + ((size_t)(bh * 2048 + i0 + row)) * 64 + csw, q_lds + cc_base * 8);
      gl_lds16(vt_base + (size_t)row * 2048 + i0 + csw, vt_lds + cc_base * 8);
    }
    __syncthreads();
    // scores ST[j,i] and P^T -> LDS
#pragma unroll
    for (int nf = 0; nf < 4; ++nf) {
      const int ir = nf * 16 + ll;
      const unsigned short* qb = q_lds + ir * 64;
      const int sw = ir & 7;
      bf16x8 b0 = *(const bf16x8*)(qb + ((lg ^ sw) * 8));
      bf16x8 b1 = *(const bf16x8*)(qb + (((4 + lg) ^ sw) * 8));
      f32x4 sa = {};
      sa = MFMA16(ka0, b0, sa, 0, 0, 0);
      sa = MFMA16(ka1, b1, sa, 0, 0, 0);
#pragma unroll
      for (int r = 0; r < 4; ++r) {
        const float p = fexp2(sa[r] - k2v[r]);
        const int j = w * 16 + lg * 4 + r;
        p_lds[j * 64 + (ir ^ ((j & 7) << 3))] = f2bf(p);
      }
    }
    // PV: A = P^T (own wave's 16 rows; within-wave LDS dependency, no barrier)
    {
      const int jr = w * 16 + ll;
      const unsigned short* pb = p_lds + jr * 64;
      const int swp = jr & 7;
      bf16x8 pa0 = *(const bf16x8*)(pb + ((lg ^ swp) * 8));
      bf16x8 pa1 = *(const bf16x8*)(pb + (((4 + lg) ^ swp) * 8));
#pragma unroll
      for (int nf = 0; nf < 4; ++nf) {
        const int dr = nf * 16 + ll;
        const unsigned short* vb = vt_lds + dr * 64;
        const int sw = dr & 7;
        bf16x8 v0 = *(const bf16x8*)(vb + ((lg ^ sw) * 8));
        bf16x8 v1 = *(const bf16x8*)(vb + (((4 + lg) ^ sw) * 8));
        oacc[nf] = MFMA16(pa0, v0, oacc[nf], 0, 0, 0);
        oacc[nf] = MFMA16(pa1, v1, oacc[nf], 0, 0, 0);
      }
    }
    __syncthreads();
  }
  const int b = bh >> 3, h2 = bh & 7;
#pragma unroll
  for (int nf = 0; nf < 4; ++nf) {
    const int d = nf * 16 + ll;
#pragma unroll
    for (int r = 0; r < 4; ++r) {
      const int j = j0 + w * 16 + lg * 4 + r;
      attnb[((size_t)(b * 2048 + j)) * 512 + h2 * 64 + d] = f2bf(oacc[nf][r]);
    }
  }
}

// ---------------------------------------------------------------------------
extern "C" void kernel_launch(void* const* d_in, const int* in_sizes, int n_in,
                              void* d_out, int out_size, void* d_ws, size_t ws_size,
                              hipStream_t stream) {
  const float* x  = (const float*)d_in[0];
  const float* Wq = (const float*)d_in[1];
  const float* bq = (const float*)d_in[2];
  const float* Wk = (const float*)d_in[3];
  const float* bk = (const float*)d_in[4];
  const float* Wv = (const float*)d_in[5];
  const float* bv = (const float*)d_in[6];
  const float* Wo = (const float*)d_in[7];
  const float* bo = (const float*)d_in[8];
  float* out = (float*)d_out;
  char* ws = (char*)d_ws;

  unsigned short* xb    = (unsigned short*)(ws);
  unsigned short* wqkvT = (unsigned short*)(ws + 8388608);
  unsigned short* woT   = (unsigned short*)(ws + 9961472);
  float*          biasp = (float*)         (ws + 10485760);
  unsigned short* q_g   = (unsigned short*)(ws + 10493952);
  unsigned short* k_g   = (unsigned short*)(ws + 18882560);
  unsigned short* v_g   = (unsigned short*)(ws + 27271168);
  unsigned short* vt_g  = (unsigned short*)(ws + 35659776);
  float*          k2_g  = (float*)         (ws + 44048384);
  float*          invl_g= (float*)         (ws + 44310528);
  unsigned short* attnb = (unsigned short*)(ws + 44572672);
  if (ws_size < (size_t)52961280) return;

  prep<<<20486, 256, 0, stream>>>(x, Wq, Wk, Wv, Wo, bq, bk, bv, xb, wqkvT, woT, biasp);
  gemm_bt<0><<<dim3(12, 64), 256, 0, stream>>>(xb, wqkvT, biasp, q_g, k_g, v_g, nullptr, 512);
  k2_kernel<<<1024, 256, 0, stream>>>(k_g, k2_g);
  pass1<<<1024, 256, 0, stream>>>(q_g, k_g, k2_g, invl_g);
  transpose_v<<<1024, 256, 0, stream>>>(v_g, invl_g, vt_g);
  pass2<<<1024, 256, 0, stream>>>(q_g, k_g, vt_g, k2_g, attnb);
  gemm_bt<1><<<dim3(4, 64), 256, 0, stream>>>(attnb, woT, bo, nullptr, nullptr, nullptr, out, 512);
}